// Round 6
// baseline (3084.835 us; speedup 1.0000x reference)
//
#include <hip/hip_runtime.h>

typedef __attribute__((ext_vector_type(8))) short short8;
typedef __attribute__((ext_vector_type(4))) float floatx4;
typedef __attribute__((ext_vector_type(2))) float float2v;

#define TOKENS 2048
#define IN_F   4096
#define OUT_F  4096
#define NITER  20

#define INV_2PI 0.15915494309189535f
#define TWO_PI  6.283185307179586f

// round-to-nearest-even f32 -> bf16 bits
__device__ __forceinline__ unsigned short f2bf(float f) {
    unsigned int u = __builtin_bit_cast(unsigned int, f);
    u += 0x7fffu + ((u >> 16) & 1u);
    return (unsigned short)(u >> 16);
}

// one fractal step in REVOLUTION units: v' = a*v + (b/2pi)*sin(2pi*v)
// (hw v_sin confirmed 2.06x faster than VALU polynomial, round-4)
__device__ __forceinline__ void step2(float2v& v, float2v a2, float2v bc2) {
    float2v s;
    s.x = __builtin_amdgcn_sinf(v.x);
    s.y = __builtin_amdgcn_sinf(v.y);
    v = __builtin_elementwise_fma(bc2, s, v * a2);
}

// ---------------------------------------------------------------------------
// Producer work unit: one thread's share of K-slab s (64 columns).
// 65536 producer threads (256 blocks x 4 waves): 4 W elems (float4, 20-iter
// sin chains) + 2 X elems (cast) per slab.  Coalesced: lanes sweep
// consecutive 16B of a row.  Same math as the verified transcribe kernel.
// ---------------------------------------------------------------------------
__device__ __forceinline__ void produce_slab(
    int s, int ptid,
    const float* __restrict__ seed, const float* __restrict__ xin,
    const float* __restrict__ da, const float* __restrict__ db,
    ushort* __restrict__ w_bf, ushort* __restrict__ x_bf)
{
    {   // W: rows ptid>>4, cols s*64 + (ptid&15)*4
        const int r  = ptid >> 4;
        const int c0 = (s << 6) + ((ptid & 15) << 2);
        const float4 v = *(const float4*)(seed + (size_t)r * IN_F + c0);
        float2v p0 = {v.x * INV_2PI, v.y * INV_2PI};
        float2v p1 = {v.z * INV_2PI, v.w * INV_2PI};
#pragma unroll
        for (int t = 0; t < NITER; t++) {
            const float a = da[t], bc = db[t] * INV_2PI;
            const float2v a2 = {a, a}, bc2 = {bc, bc};
            step2(p0, a2, bc2);
            step2(p1, a2, bc2);
        }
        ushort4 o;
        o.x = f2bf(p0.x * TWO_PI); o.y = f2bf(p0.y * TWO_PI);
        o.z = f2bf(p1.x * TWO_PI); o.w = f2bf(p1.y * TWO_PI);
        *(ushort4*)(w_bf + (size_t)r * IN_F + c0) = o;
    }
    {   // X: rows ptid>>5, cols s*64 + (ptid&31)*2
        const int r  = ptid >> 5;
        const int c0 = (s << 6) + ((ptid & 31) << 1);
        const float2 v = *(const float2*)(xin + (size_t)r * IN_F + c0);
        ushort2 o;
        o.x = f2bf(v.x); o.y = f2bf(v.y);
        *(ushort2*)(x_bf + (size_t)r * IN_F + c0) = o;
    }
}

// async 16B global -> LDS (per-lane global addr, linear wave-uniform LDS dest)
__device__ __forceinline__ void g2l16(const ushort* g, ushort* l) {
    __builtin_amdgcn_global_load_lds(
        (const __attribute__((address_space(1))) unsigned int*)g,
        (__attribute__((address_space(3))) unsigned int*)l, 16, 0, 0);
}

#define BK     64
#define BM     256
#define BN     128
#define NT     (IN_F / BK)        // 64 K-tiles = 64 slabs
#define ASLOT  (BM * BK)          // 16384 ushorts = 32 KiB
#define BSLOT  (BN * BK)          //  8192 ushorts = 16 KiB
#define LDS_USHORTS (3 * (ASLOT + BSLOT))
#define LDS_BYTES   (LDS_USHORTS * 2)        // 144 KiB (legacy gemm)
#define LDS_BYTES2  (LDS_USHORTS * 2 + 16)   // +16B rdy word (fused)
#define NPROD 1024u                          // producer waves chip-wide

// --- shared gemm macros (identical to the verified round-2 form) -----------
#define STAGE(k0v, sl)                                                        \
    {                                                                         \
        _Pragma("unroll")                                                     \
        for (int u = 0; u < 4; u++) {                                         \
            const int cb = ((u << 3) | wid) << 6;                             \
            const int r  = (cb >> 3) + (lane >> 3);                           \
            g2l16(gA + (size_t)r * IN_F + (k0v) + gcol,                       \
                  As + (sl) * ASLOT + cb * 8 + lane * 8);                     \
        }                                                                     \
        _Pragma("unroll")                                                     \
        for (int u = 0; u < 2; u++) {                                         \
            const int cb = ((u << 3) | wid) << 6;                             \
            const int r  = (cb >> 3) + (lane >> 3);                           \
            g2l16(gB + (size_t)r * IN_F + (k0v) + gcol,                       \
                  Bs + (sl) * BSLOT + cb * 8 + lane * 8);                     \
        }                                                                     \
    }

#define LOADFRAG(sl)                                                          \
    const int sa = (((q + 4 * g) & 7) ^ (fm & 7)) << 3;                       \
    _Pragma("unroll")                                                         \
    for (int i = 0; i < 8; i++)                                               \
        af[i] = *(const short8*)(As + (sl) * ASLOT + (wm + i * 16 + fm) * BK + sa); \
    _Pragma("unroll")                                                         \
    for (int j = 0; j < 4; j++)                                               \
        bf[j] = *(const short8*)(Bs + (sl) * BSLOT + (wn + j * 16 + fm) * BK + sa);

#define MFMA32()                                                              \
    __builtin_amdgcn_s_setprio(1);                                            \
    _Pragma("unroll")                                                         \
    for (int i = 0; i < 8; i++)                                               \
        _Pragma("unroll")                                                     \
        for (int j = 0; j < 4; j++)                                           \
            acc[i][j] = __builtin_amdgcn_mfma_f32_16x16x32_bf16(              \
                af[i], bf[j], acc[i][j], 0, 0, 0);                            \
    __builtin_amdgcn_s_setprio(0);

// ---------------------------------------------------------------------------
// FUSED producer-consumer kernel.  256 blocks x 12 waves:
//   waves 0..7 : the frozen round-2 gemm (3-deep ring, vmcnt 12/6/0, K-split)
//   waves 8..11: producers -- transcribe W + cast X, slab-by-slab in order.
// Cross-block slab readiness: global flags[s] (agent-scope atomics; producer
// does threadfence+atomicAdd; per-wave slab order is monotone so flags[s]
// full implies all earlier slabs full).  Gemm waves must NOT poll vmem (an
// in-order vmcnt wait on the flag load would drain the counted-vmcnt(12)
// pipeline), so wave 8 ("scout") polls the global flag and publishes to an
// LDS word; gemm waves spin on LDS (lgkm path -- drained per tile anyway).
// Barrier counts matched exactly on both role paths (128 arrivals each).
// Deadlock-free: every block holds its own producers (1 block/CU by LDS,
// 256 blocks = 256 CUs -> all resident); the minimum-tile block's needed
// slab was produced during every block's previous slot -> always progresses.
// ---------------------------------------------------------------------------
__global__ __launch_bounds__(768, 3) void fractal_fused_kernel(
    const float* __restrict__ xin, const float* __restrict__ seed,
    const float* __restrict__ da, const float* __restrict__ db,
    const float* __restrict__ bias, float* __restrict__ C,
    ushort* __restrict__ w_bf, ushort* __restrict__ x_bf,
    unsigned* __restrict__ flags)
{
    extern __shared__ ushort lds[];
    ushort* As = lds;                  // [3][ASLOT]
    ushort* Bs = lds + 3 * ASLOT;      // [3][BSLOT]
    volatile unsigned* rdy = (volatile unsigned*)(lds + LDS_USHORTS);

    const int tid  = threadIdx.x;
    const int lane = tid & 63;
    const int wid  = tid >> 6;         // 0..11

    if (tid == 0) *rdy = 0u;
    __syncthreads();                                           // barrier #1

    const int bid = blockIdx.x;
    const int jj  = bid >> 3;
    const int bn  = (bid & 7) * 4 + (jj & 3);  // bn-stripe XCD swizzle
    const int bm  = jj >> 2;

    if (wid >= 8) {
        // ------------------------- producer waves --------------------------
        const int  ptid  = (bid * 4 + (wid - 8)) * 64 + lane;  // 0..65535
        const bool scout = (wid == 8);
        // prologue: slabs 0..3
#pragma unroll 1
        for (int s = 0; s < 4; ++s) {
            produce_slab(s, ptid, seed, xin, da, db, w_bf, x_bf);
            __threadfence();
            if (lane == 0) atomicAdd(flags + s, 1u);
        }
        if (scout) {
            while (__hip_atomic_load(flags + 2, __ATOMIC_RELAXED,
                                     __HIP_MEMORY_SCOPE_AGENT) < NPROD)
                __builtin_amdgcn_s_sleep(2);
            __builtin_amdgcn_fence(__ATOMIC_ACQUIRE, "agent");
            if (lane == 0) *rdy = 3u;
        }
#pragma unroll 1
        for (int t = 0; t <= NT - 4; ++t) {                    // 61 slots
            __builtin_amdgcn_s_barrier();                      // A
            __builtin_amdgcn_s_barrier();                      // B
            if (scout) {   // publish slab t+3 readiness -> LDS
                while (__hip_atomic_load(flags + t + 3, __ATOMIC_RELAXED,
                                         __HIP_MEMORY_SCOPE_AGENT) < NPROD)
                    __builtin_amdgcn_s_sleep(2);
                __builtin_amdgcn_fence(__ATOMIC_ACQUIRE, "agent");
                if (lane == 0) *rdy = (unsigned)(t + 4);
            }
            if (t <= NT - 5) {                                 // slabs 4..63
                produce_slab(t + 4, ptid, seed, xin, da, db, w_bf, x_bf);
                __threadfence();
                if (lane == 0) atomicAdd(flags + t + 4, 1u);
            }
        }
        __builtin_amdgcn_s_barrier();                          // 3 tails
        __builtin_amdgcn_s_barrier();
        __builtin_amdgcn_s_barrier();
        __syncthreads();                                       // epilogue x2
        __syncthreads();
        return;
    }

    // --------------------------- gemm waves 0..7 ---------------------------
    const int g    = wid >> 2;         // K-group
    const int w2   = wid & 3;
    const int wm   = (w2 >> 1) << 7;
    const int wn   = (w2 & 1) << 6;
    const int fm   = lane & 15;
    const int q    = lane >> 4;
    const int gcol = (((lane & 7) ^ (lane >> 3)) << 3);

    const ushort* gA = x_bf + (size_t)(bm * BM) * IN_F;
    const ushort* gB = w_bf + (size_t)(bn * BN) * IN_F;

    floatx4 acc[8][4];
#pragma unroll
    for (int i = 0; i < 8; i++)
#pragma unroll
        for (int j = 0; j < 4; j++)
            acc[i][j] = (floatx4){0.f, 0.f, 0.f, 0.f};

    while (*rdy < 3u) { }              // slabs 0..2 ready (LDS spin)
    STAGE(0 * BK, 0);
    STAGE(1 * BK, 1);
    STAGE(2 * BK, 2);

    int st   = 0;
    int kpre = 3 * BK;
#pragma unroll 1
    for (int t = 0; t <= NT - 4; ++t) {
        asm volatile("s_waitcnt vmcnt(12)" ::: "memory");
        __builtin_amdgcn_s_barrier();                          // A
        short8 af[8], bf[4];
        LOADFRAG(st);
        asm volatile("s_waitcnt lgkmcnt(0)" ::: "memory");
        __builtin_amdgcn_s_barrier();                          // B
        while (*rdy < (unsigned)(t + 4)) { }   // slab t+3 ready (LDS spin)
        STAGE(kpre, st);
        __builtin_amdgcn_sched_barrier(0);
        MFMA32();
        kpre += BK;
        st = (st == 2) ? 0 : st + 1;
    }
    // tails: slots 1,2,0; drain 12 -> 6 -> 0
    {
        asm volatile("s_waitcnt vmcnt(12)" ::: "memory");
        __builtin_amdgcn_s_barrier();
        short8 af[8], bf[4];
        LOADFRAG(1);
        MFMA32();
    }
    {
        asm volatile("s_waitcnt vmcnt(6)" ::: "memory");
        __builtin_amdgcn_s_barrier();
        short8 af[8], bf[4];
        LOADFRAG(2);
        MFMA32();
    }
    {
        asm volatile("s_waitcnt vmcnt(0)" ::: "memory");
        __builtin_amdgcn_s_barrier();
        short8 af[8], bf[4];
        LOADFRAG(0);
        MFMA32();
    }

    // K-split reduction (ring LDS dead now)
    __syncthreads();
    floatx4* red = (floatx4*)lds;
    if (g == 1) {
#pragma unroll
        for (int i = 0; i < 8; i++)
#pragma unroll
            for (int j = 0; j < 4; j++)
                red[(size_t)(w2 * 32 + i * 4 + j) * 64 + lane] = acc[i][j];
    }
    __syncthreads();
    if (g == 0) {
        const int cn = lane & 15;
        const int cm = (lane >> 4) << 2;
        float bv[4];
#pragma unroll
        for (int j = 0; j < 4; j++)
            bv[j] = bias[bn * BN + wn + j * 16 + cn];
#pragma unroll
        for (int i = 0; i < 8; i++) {
#pragma unroll
            for (int j = 0; j < 4; j++) {
                floatx4 p = red[(size_t)(w2 * 32 + i * 4 + j) * 64 + lane];
#pragma unroll
                for (int r = 0; r < 4; r++) acc[i][j][r] += p[r];
            }
#pragma unroll
            for (int r = 0; r < 4; r++) {
                int m = bm * BM + wm + i * 16 + cm + r;
                float* crow = C + (size_t)m * OUT_F + bn * BN + wn + cn;
#pragma unroll
                for (int j = 0; j < 4; j++)
                    crow[j * 16] = acc[i][j][r] + bv[j];
            }
        }
    }
}

// ---------------------------------------------------------------------------
// Legacy two-kernel path (round-5 verified) -- fallback if workspace lacks
// slack for the flag page.
// ---------------------------------------------------------------------------
#define WBLOCKS (OUT_F * IN_F / 8 / 256)   // 8192
#define XBLOCKS (TOKENS * IN_F / 8 / 256)  // 4096

__global__ __launch_bounds__(256) void transcribe_fused_kernel(
    const float4* __restrict__ seed, const float4* __restrict__ xin,
    const float* __restrict__ da, const float* __restrict__ db,
    short8* __restrict__ w_out, short8* __restrict__ x_out)
{
    const int b = blockIdx.x;
    short8 o;
    if (b < WBLOCKS) {
        int i = b * 256 + threadIdx.x;
        float4 U = ((const float4*)seed)[2 * i];
        float4 V = ((const float4*)seed)[2 * i + 1];
        float2v p0 = {U.x, U.y}, p1 = {U.z, U.w};
        float2v p2 = {V.x, V.y}, p3 = {V.z, V.w};
        const float2v kinv = {INV_2PI, INV_2PI};
        p0 *= kinv; p1 *= kinv; p2 *= kinv; p3 *= kinv;
#pragma unroll
        for (int t = 0; t < NITER; t++) {
            float a = da[t], bc = db[t] * INV_2PI;
            float2v a2 = {a, a}, bc2 = {bc, bc};
            step2(p0, a2, bc2); step2(p1, a2, bc2);
            step2(p2, a2, bc2); step2(p3, a2, bc2);
        }
        o[0] = (short)f2bf(p0.x * TWO_PI); o[1] = (short)f2bf(p0.y * TWO_PI);
        o[2] = (short)f2bf(p1.x * TWO_PI); o[3] = (short)f2bf(p1.y * TWO_PI);
        o[4] = (short)f2bf(p2.x * TWO_PI); o[5] = (short)f2bf(p2.y * TWO_PI);
        o[6] = (short)f2bf(p3.x * TWO_PI); o[7] = (short)f2bf(p3.y * TWO_PI);
        w_out[i] = o;
    } else {
        int i = (b - WBLOCKS) * 256 + threadIdx.x;
        float4 u = xin[2 * i];
        float4 v = xin[2 * i + 1];
        o[0] = (short)f2bf(u.x); o[1] = (short)f2bf(u.y);
        o[2] = (short)f2bf(u.z); o[3] = (short)f2bf(u.w);
        o[4] = (short)f2bf(v.x); o[5] = (short)f2bf(v.y);
        o[6] = (short)f2bf(v.z); o[7] = (short)f2bf(v.w);
        x_out[i] = o;
    }
}

__global__ __launch_bounds__(512, 2) void gemm_bt_kernel(
    const ushort* __restrict__ A,
    const ushort* __restrict__ B,
    const float* __restrict__ bias,
    float* __restrict__ C)
{
    extern __shared__ ushort lds[];
    ushort* As = lds;
    ushort* Bs = lds + 3 * ASLOT;

    const int tid  = threadIdx.x;
    const int lane = tid & 63;
    const int wid  = tid >> 6;
    const int g    = wid >> 2;
    const int w2   = wid & 3;
    const int wm   = (w2 >> 1) << 7;
    const int wn   = (w2 & 1) << 6;
    const int fm   = lane & 15;
    const int q    = lane >> 4;

    const int bid = blockIdx.x;
    const int jj  = bid >> 3;
    const int bn  = (bid & 7) * 4 + (jj & 3);
    const int bm  = jj >> 2;

    const int gcol = (((lane & 7) ^ (lane >> 3)) << 3);
    const ushort* gA = A + (size_t)(bm * BM) * IN_F;
    const ushort* gB = B + (size_t)(bn * BN) * IN_F;

    floatx4 acc[8][4];
#pragma unroll
    for (int i = 0; i < 8; i++)
#pragma unroll
        for (int j = 0; j < 4; j++)
            acc[i][j] = (floatx4){0.f, 0.f, 0.f, 0.f};

    STAGE(0 * BK, 0);
    STAGE(1 * BK, 1);
    STAGE(2 * BK, 2);

    int st   = 0;
    int kpre = 3 * BK;
#pragma unroll 1
    for (int t = 0; t <= NT - 4; ++t) {
        asm volatile("s_waitcnt vmcnt(12)" ::: "memory");
        __builtin_amdgcn_s_barrier();
        short8 af[8], bf[4];
        LOADFRAG(st);
        asm volatile("s_waitcnt lgkmcnt(0)" ::: "memory");
        __builtin_amdgcn_s_barrier();
        STAGE(kpre, st);
        __builtin_amdgcn_sched_barrier(0);
        MFMA32();
        kpre += BK;
        st = (st == 2) ? 0 : st + 1;
    }
    {
        asm volatile("s_waitcnt vmcnt(12)" ::: "memory");
        __builtin_amdgcn_s_barrier();
        short8 af[8], bf[4];
        LOADFRAG(1);
        MFMA32();
    }
    {
        asm volatile("s_waitcnt vmcnt(6)" ::: "memory");
        __builtin_amdgcn_s_barrier();
        short8 af[8], bf[4];
        LOADFRAG(2);
        MFMA32();
    }
    {
        asm volatile("s_waitcnt vmcnt(0)" ::: "memory");
        __builtin_amdgcn_s_barrier();
        short8 af[8], bf[4];
        LOADFRAG(0);
        MFMA32();
    }

    __syncthreads();
    floatx4* red = (floatx4*)lds;
    if (g == 1) {
#pragma unroll
        for (int i = 0; i < 8; i++)
#pragma unroll
            for (int j = 0; j < 4; j++)
                red[(size_t)(w2 * 32 + i * 4 + j) * 64 + lane] = acc[i][j];
    }
    __syncthreads();
    if (g == 0) {
        const int cn = lane & 15;
        const int cm = (lane >> 4) << 2;
        float bv[4];
#pragma unroll
        for (int j = 0; j < 4; j++)
            bv[j] = bias[bn * BN + wn + j * 16 + cn];
#pragma unroll
        for (int i = 0; i < 8; i++) {
#pragma unroll
            for (int j = 0; j < 4; j++) {
                floatx4 p = red[(size_t)(w2 * 32 + i * 4 + j) * 64 + lane];
#pragma unroll
                for (int r = 0; r < 4; r++) acc[i][j][r] += p[r];
            }
#pragma unroll
            for (int r = 0; r < 4; r++) {
                int m = bm * BM + wm + i * 16 + cm + r;
                float* crow = C + (size_t)m * OUT_F + bn * BN + wn + cn;
#pragma unroll
                for (int j = 0; j < 4; j++)
                    crow[j * 16] = acc[i][j][r] + bv[j];
            }
        }
    }
}

#undef STAGE
#undef LOADFRAG
#undef MFMA32

extern "C" void kernel_launch(void* const* d_in, const int* in_sizes, int n_in,
                              void* d_out, int out_size, void* d_ws, size_t ws_size,
                              hipStream_t stream) {
    const float* x    = (const float*)d_in[0];   // [2048, 4096]
    const float* seed = (const float*)d_in[1];   // [4096, 4096]
    const float* da   = (const float*)d_in[2];   // [20]
    const float* db   = (const float*)d_in[3];   // [20]
    const float* bias = (const float*)d_in[4];   // [4096]
    float* out        = (float*)d_out;           // [2048, 4096]

    ushort* w_bf = (ushort*)d_ws;                      // 32 MiB
    ushort* x_bf = w_bf + (size_t)OUT_F * IN_F;        // 16 MiB
    const size_t used = ((size_t)OUT_F * IN_F + (size_t)TOKENS * IN_F) * 2;

    static bool lds_attr_set = false;
    if (!lds_attr_set) {
        hipFuncSetAttribute(reinterpret_cast<const void*>(gemm_bt_kernel),
                            hipFuncAttributeMaxDynamicSharedMemorySize,
                            LDS_BYTES);
        hipFuncSetAttribute(reinterpret_cast<const void*>(fractal_fused_kernel),
                            hipFuncAttributeMaxDynamicSharedMemorySize,
                            LDS_BYTES2);
        lds_attr_set = true;
    }

    if (ws_size >= used + 4096) {
        // flag page: last 4 KiB of workspace (aligned down to 256B)
        unsigned* flags = (unsigned*)((char*)d_ws + ((ws_size - 4096) & ~(size_t)255));
        hipMemsetAsync(flags, 0, 256, stream);
        fractal_fused_kernel<<<dim3(256), dim3(768), LDS_BYTES2, stream>>>(
            x, seed, da, db, bias, out, w_bf, x_bf, flags);
    } else {
        // fallback: round-5 two-kernel path
        transcribe_fused_kernel<<<WBLOCKS + XBLOCKS, 256, 0, stream>>>(
            (const float4*)seed, (const float4*)x, da, db,
            (short8*)w_bf, (short8*)x_bf);
        gemm_bt_kernel<<<dim3(32 * 8), dim3(512), LDS_BYTES, stream>>>(
            x_bf, w_bf, bias, out);
    }
}

// Round 7
// 370.946 us; speedup vs baseline: 8.3161x; 8.3161x over previous
//
#include <hip/hip_runtime.h>

typedef __attribute__((ext_vector_type(8))) short short8;
typedef __attribute__((ext_vector_type(4))) float floatx4;
typedef __attribute__((ext_vector_type(2))) float float2v;

#define TOKENS 2048
#define IN_F   4096
#define OUT_F  4096
#define NITER  20

#define INV_2PI 0.15915494309189535f
#define TWO_PI  6.283185307179586f

// round-to-nearest-even f32 -> bf16 bits
__device__ __forceinline__ unsigned short f2bf(float f) {
    unsigned int u = __builtin_bit_cast(unsigned int, f);
    u += 0x7fffu + ((u >> 16) & 1u);
    return (unsigned short)(u >> 16);
}

// one fractal step in REVOLUTION units: v' = a*v + (b/2pi)*sin(2pi*v)
// (hw v_sin confirmed 2.06x faster than VALU polynomial, round-4)
__device__ __forceinline__ void step2(float2v& v, float2v a2, float2v bc2) {
    float2v s;
    s.x = __builtin_amdgcn_sinf(v.x);
    s.y = __builtin_amdgcn_sinf(v.y);
    v = __builtin_elementwise_fma(bc2, s, v * a2);
}

// ---------------------------------------------------------------------------
// Round-6 post-mortem: producer-consumer fusion via same-address global
// atomics + per-wave threadfence = 3.38ms (1024-wave atomic serialization
// ~50us/slab + L2 writeback storms: WRITE_SIZE 1.1GB).  Overlap is kept but
// ALL in-kernel sync is removed: K is split in half and the stream's
// kernel-boundary ordering is the only handoff.
//   T1 : transcribe W / cast X, cols [0,2048)          (~24us)
//   MID: gemm K-tiles [0,32)  (+bias)  || producer waves transcribe/cast
//        cols [2048,4096) -- producers have NO consumer in this kernel,
//        they only match the gemm waves' barrier arrivals (proven sound r6)
//   G2 : gemm K-tiles [32,64), epilogue C += acc
// ---------------------------------------------------------------------------

// ------------------------- T1: first-half transcribe -----------------------
#define T1_WBLK 4096   // 4096 rows x 2048 cols / 8 per thread / 256
#define T1_XBLK 2048   // 2048 rows x 2048 cols / 8 per thread / 256

__global__ __launch_bounds__(256) void transcribe_h1_kernel(
    const float* __restrict__ seed, const float* __restrict__ xin,
    const float* __restrict__ da, const float* __restrict__ db,
    ushort* __restrict__ w_bf, ushort* __restrict__ x_bf)
{
    const int b = blockIdx.x;
    short8 o;
    if (b < T1_WBLK) {
        const int i   = b * 256 + threadIdx.x;      // [0, 1048576)
        const int row = i >> 8;
        const int col = (i & 255) << 3;             // [0, 2048)
        const float* src = seed + (size_t)row * IN_F + col;
        const float4 U = *(const float4*)src;
        const float4 V = *(const float4*)(src + 4);
        float2v p0 = {U.x * INV_2PI, U.y * INV_2PI};
        float2v p1 = {U.z * INV_2PI, U.w * INV_2PI};
        float2v p2 = {V.x * INV_2PI, V.y * INV_2PI};
        float2v p3 = {V.z * INV_2PI, V.w * INV_2PI};
#pragma unroll
        for (int t = 0; t < NITER; t++) {
            const float a = da[t], bc = db[t] * INV_2PI;
            const float2v a2 = {a, a}, bc2 = {bc, bc};
            step2(p0, a2, bc2); step2(p1, a2, bc2);
            step2(p2, a2, bc2); step2(p3, a2, bc2);
        }
        o[0] = (short)f2bf(p0.x * TWO_PI); o[1] = (short)f2bf(p0.y * TWO_PI);
        o[2] = (short)f2bf(p1.x * TWO_PI); o[3] = (short)f2bf(p1.y * TWO_PI);
        o[4] = (short)f2bf(p2.x * TWO_PI); o[5] = (short)f2bf(p2.y * TWO_PI);
        o[6] = (short)f2bf(p3.x * TWO_PI); o[7] = (short)f2bf(p3.y * TWO_PI);
        *(short8*)(w_bf + (size_t)row * IN_F + col) = o;
    } else {
        const int i   = (b - T1_WBLK) * 256 + threadIdx.x;  // [0, 524288)
        const int row = i >> 8;
        const int col = (i & 255) << 3;
        const float* src = xin + (size_t)row * IN_F + col;
        const float4 u = *(const float4*)src;
        const float4 v = *(const float4*)(src + 4);
        o[0] = (short)f2bf(u.x); o[1] = (short)f2bf(u.y);
        o[2] = (short)f2bf(u.z); o[3] = (short)f2bf(u.w);
        o[4] = (short)f2bf(v.x); o[5] = (short)f2bf(v.y);
        o[6] = (short)f2bf(v.z); o[7] = (short)f2bf(v.w);
        *(short8*)(x_bf + (size_t)row * IN_F + col) = o;
    }
}

// ---------------- producer work units (second-half columns) ----------------
// W half2: 4096 rows x 512 float4/row = 2097152 f4 -> 32 per producer thread
// X half2: 2048 rows x 512 float4/row = 1048576 f4 -> 16 per producer thread
__device__ __forceinline__ void produceW_f4(
    int idx, const float* __restrict__ seed,
    const float* __restrict__ da, const float* __restrict__ db,
    ushort* __restrict__ w_bf)
{
    const int row = idx >> 9;
    const int col = 2048 + ((idx & 511) << 2);
    const float4 v = *(const float4*)(seed + (size_t)row * IN_F + col);
    float2v p0 = {v.x * INV_2PI, v.y * INV_2PI};
    float2v p1 = {v.z * INV_2PI, v.w * INV_2PI};
#pragma unroll
    for (int t = 0; t < NITER; t++) {
        const float a = da[t], bc = db[t] * INV_2PI;
        const float2v a2 = {a, a}, bc2 = {bc, bc};
        step2(p0, a2, bc2); step2(p1, a2, bc2);
    }
    ushort4 o;
    o.x = f2bf(p0.x * TWO_PI); o.y = f2bf(p0.y * TWO_PI);
    o.z = f2bf(p1.x * TWO_PI); o.w = f2bf(p1.y * TWO_PI);
    *(ushort4*)(w_bf + (size_t)row * IN_F + col) = o;
}

__device__ __forceinline__ void produceX_f4(
    int idx, const float* __restrict__ xin, ushort* __restrict__ x_bf)
{
    const int row = idx >> 9;
    const int col = 2048 + ((idx & 511) << 2);
    const float4 v = *(const float4*)(xin + (size_t)row * IN_F + col);
    ushort4 o;
    o.x = f2bf(v.x); o.y = f2bf(v.y); o.z = f2bf(v.z); o.w = f2bf(v.w);
    *(ushort4*)(x_bf + (size_t)row * IN_F + col) = o;
}

// async 16B global -> LDS (per-lane global addr, linear wave-uniform LDS dest)
__device__ __forceinline__ void g2l16(const ushort* g, ushort* l) {
    __builtin_amdgcn_global_load_lds(
        (const __attribute__((address_space(1))) unsigned int*)g,
        (__attribute__((address_space(3))) unsigned int*)l, 16, 0, 0);
}

// ---------------------- gemm (verified round-2/5 form) ---------------------
#define BK     64
#define BM     256
#define BN     128
#define NT2    32                 // K-tiles per half
#define ASLOT  (BM * BK)          // 16384 ushorts = 32 KiB
#define BSLOT  (BN * BK)          //  8192 ushorts = 16 KiB
#define LDS_BYTES (3 * (ASLOT + BSLOT) * 2)   // 144 KiB

#define STAGE(k0v, sl)                                                        \
    {                                                                         \
        _Pragma("unroll")                                                     \
        for (int u = 0; u < 4; u++) {                                         \
            const int cb = ((u << 3) | wid) << 6;                             \
            const int r  = (cb >> 3) + (lane >> 3);                           \
            g2l16(gA + (size_t)r * IN_F + (k0v) + gcol,                       \
                  As + (sl) * ASLOT + cb * 8 + lane * 8);                     \
        }                                                                     \
        _Pragma("unroll")                                                     \
        for (int u = 0; u < 2; u++) {                                         \
            const int cb = ((u << 3) | wid) << 6;                             \
            const int r  = (cb >> 3) + (lane >> 3);                           \
            g2l16(gB + (size_t)r * IN_F + (k0v) + gcol,                       \
                  Bs + (sl) * BSLOT + cb * 8 + lane * 8);                     \
        }                                                                     \
    }

#define LOADFRAG(sl)                                                          \
    const int sa = (((q + 4 * g) & 7) ^ (fm & 7)) << 3;                       \
    _Pragma("unroll")                                                         \
    for (int i = 0; i < 8; i++)                                               \
        af[i] = *(const short8*)(As + (sl) * ASLOT + (wm + i * 16 + fm) * BK + sa); \
    _Pragma("unroll")                                                         \
    for (int j = 0; j < 4; j++)                                               \
        bf[j] = *(const short8*)(Bs + (sl) * BSLOT + (wn + j * 16 + fm) * BK + sa);

#define MFMA32()                                                              \
    __builtin_amdgcn_s_setprio(1);                                            \
    _Pragma("unroll")                                                         \
    for (int i = 0; i < 8; i++)                                               \
        _Pragma("unroll")                                                     \
        for (int j = 0; j < 4; j++)                                           \
            acc[i][j] = __builtin_amdgcn_mfma_f32_16x16x32_bf16(              \
                af[i], bf[j], acc[i][j], 0, 0, 0);                            \
    __builtin_amdgcn_s_setprio(0);

// gemm body over K-tiles [0,NT2) of gA/gB (callers pre-offset the K origin).
// Barriers: 29x2 (loop) + 3 (tails) = 61 s_barrier, + 2 __syncthreads.
#define GEMM_BODY()                                                           \
    floatx4 acc[8][4];                                                        \
    _Pragma("unroll")                                                         \
    for (int i = 0; i < 8; i++)                                               \
        _Pragma("unroll")                                                     \
        for (int j = 0; j < 4; j++)                                           \
            acc[i][j] = (floatx4){0.f, 0.f, 0.f, 0.f};                        \
    STAGE(0 * BK, 0);                                                         \
    STAGE(1 * BK, 1);                                                         \
    STAGE(2 * BK, 2);                                                         \
    int st   = 0;                                                             \
    int kpre = 3 * BK;                                                        \
    _Pragma("unroll 1")                                                       \
    for (int t = 0; t <= NT2 - 4; ++t) {   /* 29 iters, stages tiles 3..31 */ \
        asm volatile("s_waitcnt vmcnt(12)" ::: "memory");                     \
        __builtin_amdgcn_s_barrier();                                         \
        short8 af[8], bf[4];                                                  \
        LOADFRAG(st);                                                         \
        asm volatile("s_waitcnt lgkmcnt(0)" ::: "memory");                    \
        __builtin_amdgcn_s_barrier();                                         \
        STAGE(kpre, st);                                                      \
        __builtin_amdgcn_sched_barrier(0);                                    \
        MFMA32();                                                             \
        kpre += BK;                                                           \
        st = (st == 2) ? 0 : st + 1;                                          \
    }                                                                         \
    /* tails: tiles 29,30,31 -> slots 2,0,1; drain 12 -> 6 -> 0 */            \
    {                                                                         \
        asm volatile("s_waitcnt vmcnt(12)" ::: "memory");                     \
        __builtin_amdgcn_s_barrier();                                         \
        short8 af[8], bf[4];                                                  \
        LOADFRAG(2);                                                          \
        MFMA32();                                                             \
    }                                                                         \
    {                                                                         \
        asm volatile("s_waitcnt vmcnt(6)" ::: "memory");                      \
        __builtin_amdgcn_s_barrier();                                         \
        short8 af[8], bf[4];                                                  \
        LOADFRAG(0);                                                          \
        MFMA32();                                                             \
    }                                                                         \
    {                                                                         \
        asm volatile("s_waitcnt vmcnt(0)" ::: "memory");                      \
        __builtin_amdgcn_s_barrier();                                         \
        short8 af[8], bf[4];                                                  \
        LOADFRAG(1);                                                          \
        MFMA32();                                                             \
    }                                                                         \
    /* K-split reduction: group1 parks partials, group0 finishes */           \
    __syncthreads();                                                          \
    floatx4* red = (floatx4*)lds;                                             \
    if (g == 1) {                                                             \
        _Pragma("unroll")                                                     \
        for (int i = 0; i < 8; i++)                                           \
            _Pragma("unroll")                                                 \
            for (int j = 0; j < 4; j++)                                       \
                red[(size_t)(w2 * 32 + i * 4 + j) * 64 + lane] = acc[i][j];   \
    }                                                                         \
    __syncthreads();

// ------------------- MID: gemm K[0,32) + producer waves --------------------
__global__ __launch_bounds__(768, 3) void fractal_mid_kernel(
    const float* __restrict__ xin, const float* __restrict__ seed,
    const float* __restrict__ da, const float* __restrict__ db,
    const float* __restrict__ bias, float* __restrict__ C,
    ushort* __restrict__ w_bf, ushort* __restrict__ x_bf)
{
    extern __shared__ ushort lds[];
    ushort* As = lds;
    ushort* Bs = lds + 3 * ASLOT;

    const int tid  = threadIdx.x;
    const int lane = tid & 63;
    const int wid  = tid >> 6;         // 0..11
    const int bid  = blockIdx.x;

    if (wid >= 8) {
        // producer waves: cols [2048,4096), no in-kernel consumer.
        // 48 work units spread across the 61 barrier arrivals the gemm makes.
        const int pid = (bid * 4 + (wid - 8)) * 64 + lane;   // [0, 65536)
#pragma unroll 1
        for (int i = 0; i < 61; ++i) {
            if (i < 32)      produceW_f4(pid + i * 65536, seed, da, db, w_bf);
            else if (i < 48) produceX_f4(pid + (i - 32) * 65536, xin, x_bf);
            __builtin_amdgcn_s_barrier();
        }
        __syncthreads();
        __syncthreads();
        return;
    }

    // gemm waves 0..7: K-tiles [0,32), verified structure
    const int g    = wid >> 2;
    const int w2   = wid & 3;
    const int wm   = (w2 >> 1) << 7;
    const int wn   = (w2 & 1) << 6;
    const int fm   = lane & 15;
    const int q    = lane >> 4;
    const int jj   = bid >> 3;
    const int bn   = (bid & 7) * 4 + (jj & 3);  // bn-stripe XCD swizzle
    const int bm   = jj >> 2;
    const int gcol = (((lane & 7) ^ (lane >> 3)) << 3);

    const ushort* gA = x_bf + (size_t)(bm * BM) * IN_F;      // K origin 0
    const ushort* gB = w_bf + (size_t)(bn * BN) * IN_F;

    GEMM_BODY();

    if (g == 0) {   // epilogue: C = partial0 + bias
        const int cn = lane & 15;
        const int cm = (lane >> 4) << 2;
        float bv[4];
#pragma unroll
        for (int j = 0; j < 4; j++)
            bv[j] = bias[bn * BN + wn + j * 16 + cn];
#pragma unroll
        for (int i = 0; i < 8; i++) {
#pragma unroll
            for (int j = 0; j < 4; j++) {
                floatx4 p = red[(size_t)(w2 * 32 + i * 4 + j) * 64 + lane];
#pragma unroll
                for (int r = 0; r < 4; r++) acc[i][j][r] += p[r];
            }
#pragma unroll
            for (int r = 0; r < 4; r++) {
                int m = bm * BM + wm + i * 16 + cm + r;
                float* crow = C + (size_t)m * OUT_F + bn * BN + wn + cn;
#pragma unroll
                for (int j = 0; j < 4; j++)
                    crow[j * 16] = acc[i][j][r] + bv[j];
            }
        }
    }
}

// --------------------- G2: gemm K[32,64), C-accumulate ---------------------
__global__ __launch_bounds__(512, 2) void gemm_k2_kernel(
    const ushort* __restrict__ A,
    const ushort* __restrict__ B,
    float* __restrict__ C)
{
    extern __shared__ ushort lds[];
    ushort* As = lds;
    ushort* Bs = lds + 3 * ASLOT;

    const int tid  = threadIdx.x;
    const int lane = tid & 63;
    const int wid  = tid >> 6;
    const int g    = wid >> 2;
    const int w2   = wid & 3;
    const int wm   = (w2 >> 1) << 7;
    const int wn   = (w2 & 1) << 6;
    const int fm   = lane & 15;
    const int q    = lane >> 4;
    const int bid  = blockIdx.x;
    const int jj   = bid >> 3;
    const int bn   = (bid & 7) * 4 + (jj & 3);
    const int bm   = jj >> 2;
    const int gcol = (((lane & 7) ^ (lane >> 3)) << 3);

    const ushort* gA = A + (size_t)(bm * BM) * IN_F + 2048;  // K origin 2048
    const ushort* gB = B + (size_t)(bn * BN) * IN_F + 2048;

    GEMM_BODY();

    if (g == 0) {   // epilogue: C += partial1
        const int cn = lane & 15;
        const int cm = (lane >> 4) << 2;
#pragma unroll
        for (int i = 0; i < 8; i++) {
#pragma unroll
            for (int j = 0; j < 4; j++) {
                floatx4 p = red[(size_t)(w2 * 32 + i * 4 + j) * 64 + lane];
#pragma unroll
                for (int r = 0; r < 4; r++) acc[i][j][r] += p[r];
            }
#pragma unroll
            for (int r = 0; r < 4; r++) {
                int m = bm * BM + wm + i * 16 + cm + r;
                float* crow = C + (size_t)m * OUT_F + bn * BN + wn + cn;
#pragma unroll
                for (int j = 0; j < 4; j++)
                    crow[j * 16] += acc[i][j][r];
            }
        }
    }
}

#undef STAGE
#undef LOADFRAG
#undef MFMA32
#undef GEMM_BODY

extern "C" void kernel_launch(void* const* d_in, const int* in_sizes, int n_in,
                              void* d_out, int out_size, void* d_ws, size_t ws_size,
                              hipStream_t stream) {
    const float* x    = (const float*)d_in[0];   // [2048, 4096]
    const float* seed = (const float*)d_in[1];   // [4096, 4096]
    const float* da   = (const float*)d_in[2];   // [20]
    const float* db   = (const float*)d_in[3];   // [20]
    const float* bias = (const float*)d_in[4];   // [4096]
    float* out        = (float*)d_out;           // [2048, 4096]

    ushort* w_bf = (ushort*)d_ws;                      // 32 MiB
    ushort* x_bf = w_bf + (size_t)OUT_F * IN_F;        // 16 MiB

    static bool lds_attr_set = false;
    if (!lds_attr_set) {
        hipFuncSetAttribute(reinterpret_cast<const void*>(fractal_mid_kernel),
                            hipFuncAttributeMaxDynamicSharedMemorySize,
                            LDS_BYTES);
        hipFuncSetAttribute(reinterpret_cast<const void*>(gemm_k2_kernel),
                            hipFuncAttributeMaxDynamicSharedMemorySize,
                            LDS_BYTES);
        lds_attr_set = true;
    }

    // 1) first-half transcribe/cast (cols 0..2047)
    transcribe_h1_kernel<<<T1_WBLK + T1_XBLK, 256, 0, stream>>>(
        seed, x, da, db, w_bf, x_bf);
    // 2) gemm K[0,32) || produce cols 2048..4095  (handoff = kernel boundary)
    fractal_mid_kernel<<<dim3(256), dim3(768), LDS_BYTES, stream>>>(
        x, seed, da, db, bias, out, w_bf, x_bf);
    // 3) gemm K[32,64), accumulate into C
    gemm_k2_kernel<<<dim3(256), dim3(512), LDS_BYTES, stream>>>(
        x_bf, w_bf, out);
}

// Round 10
// 207.232 us; speedup vs baseline: 14.8859x; 1.7900x over previous
//
#include <hip/hip_runtime.h>

typedef __attribute__((ext_vector_type(8))) short short8;
typedef __attribute__((ext_vector_type(4))) float floatx4;
typedef __attribute__((ext_vector_type(2))) float float2v;

#define TOKENS 2048
#define IN_F   4096
#define OUT_F  4096
#define NITER  20

#define INV_2PI 0.15915494309189535f
#define TWO_PI  6.283185307179586f

// round-to-nearest-even f32 -> bf16 bits
__device__ __forceinline__ unsigned short f2bf(float f) {
    unsigned int u = __builtin_bit_cast(unsigned int, f);
    u += 0x7fffu + ((u >> 16) & 1u);
    return (unsigned short)(u >> 16);
}

// ---------------------------------------------------------------------------
// VERIFIED round-5 configuration, resubmitted verbatim (208.7us; session band
// 207-209 across equivalent configs).  Rounds 6-9 post-mortems:
//  - R6 producer-consumer fusion w/ global atomics: 3.08ms (atomic serialize
//    + L2 writeback storm, WRITE 1.1GB).
//  - R7 fused kernel at launch_bounds(768,3): scratch spill (VGPR cap 170 <
//    238 needed) -> WRITE 323MB, 371us.
//  - R8/R9 wave-role-split fix: same source killed the container twice
//    (source-correlated; divergent-barrier structure suspect).
// The overlap prize (~20us of 209) does not justify the measured risk.
//
// Budget (calibrated R0-R5): gemm 75us (MfmaUtil ~37%, three schedule
// variants identical -> structural plateau for this tile class); transcribe
// ~48us (v_sin ~11cyc/wave-instr on the VALU issue pipe, 336M sins
// sequential/irreducible; VALU-poly 2.06x worse, R4); fixed harness
// residual ~85us.
// ---------------------------------------------------------------------------
__device__ __forceinline__ void step2(float2v& v, float2v a2, float2v bc2) {
    float2v s;
    s.x = __builtin_amdgcn_sinf(v.x);
    s.y = __builtin_amdgcn_sinf(v.y);
    v = __builtin_elementwise_fma(bc2, s, v * a2);
}

#define WBLOCKS (OUT_F * IN_F / 8 / 256)   // 8192
#define XBLOCKS (TOKENS * IN_F / 8 / 256)  // 4096

// Fused: blocks [0,8192) transcribe seed->w_bf (20 iters); [8192,12288) cast x->x_bf.
__global__ __launch_bounds__(256) void transcribe_fused_kernel(
    const float4* __restrict__ seed, const float4* __restrict__ xin,
    const float* __restrict__ da, const float* __restrict__ db,
    short8* __restrict__ w_out, short8* __restrict__ x_out)
{
    const int b = blockIdx.x;
    short8 o;
    if (b < WBLOCKS) {
        int i = b * 256 + threadIdx.x;
        float4 U = seed[2 * i];
        float4 V = seed[2 * i + 1];
        float2v p0 = {U.x, U.y}, p1 = {U.z, U.w};
        float2v p2 = {V.x, V.y}, p3 = {V.z, V.w};
        const float2v kinv = {INV_2PI, INV_2PI};
        p0 *= kinv; p1 *= kinv; p2 *= kinv; p3 *= kinv;   // v_pk_mul_f32
#pragma unroll
        for (int t = 0; t < NITER; t++) {
            float a = da[t], bc = db[t] * INV_2PI;
            float2v a2 = {a, a}, bc2 = {bc, bc};
            step2(p0, a2, bc2);
            step2(p1, a2, bc2);
            step2(p2, a2, bc2);
            step2(p3, a2, bc2);
        }
        o[0] = (short)f2bf(p0.x * TWO_PI); o[1] = (short)f2bf(p0.y * TWO_PI);
        o[2] = (short)f2bf(p1.x * TWO_PI); o[3] = (short)f2bf(p1.y * TWO_PI);
        o[4] = (short)f2bf(p2.x * TWO_PI); o[5] = (short)f2bf(p2.y * TWO_PI);
        o[6] = (short)f2bf(p3.x * TWO_PI); o[7] = (short)f2bf(p3.y * TWO_PI);
        w_out[i] = o;
    } else {
        int i = (b - WBLOCKS) * 256 + threadIdx.x;
        float4 u = xin[2 * i];
        float4 v = xin[2 * i + 1];
        o[0] = (short)f2bf(u.x); o[1] = (short)f2bf(u.y);
        o[2] = (short)f2bf(u.z); o[3] = (short)f2bf(u.w);
        o[4] = (short)f2bf(v.x); o[5] = (short)f2bf(v.y);
        o[6] = (short)f2bf(v.z); o[7] = (short)f2bf(v.w);
        x_out[i] = o;
    }
}

// async 16B global -> LDS (per-lane global addr, linear wave-uniform LDS dest)
__device__ __forceinline__ void g2l16(const ushort* g, ushort* l) {
    __builtin_amdgcn_global_load_lds(
        (const __attribute__((address_space(1))) unsigned int*)g,
        (__attribute__((address_space(3))) unsigned int*)l, 16, 0, 0);
}

// ---------------------------------------------------------------------------
// GEMM: frozen round-2 form (74.5-82us across runs = ~900 TF, MfmaUtil ~37%,
// conflicts 0, FETCH 82MB).  Counted-vmcnt 3-deep ring, K-split 2x(2x2)
// waves, bn-stripe XCD swizzle.  Three schedule variants measured identical
// -> structural plateau; left untouched.
// ---------------------------------------------------------------------------
#define BK     64
#define BM     256
#define BN     128
#define NT     (IN_F / BK)        // 64 K-tiles
#define ASLOT  (BM * BK)          // 16384 ushorts = 32 KiB
#define BSLOT  (BN * BK)          //  8192 ushorts = 16 KiB
#define LDS_BYTES (3 * (ASLOT + BSLOT) * 2)   // 147456 B = 144 KiB

__global__ __launch_bounds__(512, 2) void gemm_bt_kernel(
    const ushort* __restrict__ A,
    const ushort* __restrict__ B,
    const float* __restrict__ bias,
    float* __restrict__ C)
{
    extern __shared__ ushort lds[];
    ushort* As = lds;                  // [3][ASLOT]
    ushort* Bs = lds + 3 * ASLOT;      // [3][BSLOT]

    const int tid  = threadIdx.x;
    const int lane = tid & 63;
    const int wid  = tid >> 6;         // 0..7
    const int g    = wid >> 2;         // K-group: 0 -> k[0,32), 1 -> k[32,64)
    const int w2   = wid & 3;          // spatial wave 2x2
    const int wm   = (w2 >> 1) << 7;   // 0/128
    const int wn   = (w2 & 1) << 6;    // 0/64
    const int fm   = lane & 15;
    const int q    = lane >> 4;        // 0..3

    // XCD-aware swizzle, bn-stripes (verified: FETCH 139->82 MB)
    const int bid = blockIdx.x;
    const int jj  = bid >> 3;                  // 0..31
    const int bn  = (bid & 7) * 4 + (jj & 3);  // 0..31
    const int bm  = jj >> 2;                   // 0..7

    // staging: wave-instr covers 64 consecutive 16B chunks (8 rows x 8 segs);
    // lane = (row&7)*8 + pseg; global source segment = pseg ^ (row&7).
    const int gcol = (((lane & 7) ^ (lane >> 3)) << 3);

    const ushort* gA = A + (size_t)(bm * BM) * IN_F;
    const ushort* gB = B + (size_t)(bn * BN) * IN_F;

    floatx4 acc[8][4];
#pragma unroll
    for (int i = 0; i < 8; i++)
#pragma unroll
        for (int j = 0; j < 4; j++)
            acc[i][j] = (floatx4){0.f, 0.f, 0.f, 0.f};

    // 6 VMEM instrs per wave per tile (vmcnt counts these).
#define STAGE(k0v, sl)                                                        \
    {                                                                         \
        _Pragma("unroll")                                                     \
        for (int u = 0; u < 4; u++) {                                         \
            const int cb = ((u << 3) | wid) << 6;                             \
            const int r  = (cb >> 3) + (lane >> 3);                           \
            g2l16(gA + (size_t)r * IN_F + (k0v) + gcol,                       \
                  As + (sl) * ASLOT + cb * 8 + lane * 8);                     \
        }                                                                     \
        _Pragma("unroll")                                                     \
        for (int u = 0; u < 2; u++) {                                         \
            const int cb = ((u << 3) | wid) << 6;                             \
            const int r  = (cb >> 3) + (lane >> 3);                           \
            g2l16(gB + (size_t)r * IN_F + (k0v) + gcol,                       \
                  Bs + (sl) * BSLOT + cb * 8 + lane * 8);                     \
        }                                                                     \
    }

    // 12 x ds_read_b128: this wave's K-slice (= group g) of slot sl.
#define LOADFRAG(sl)                                                          \
    const int sa = (((q + 4 * g) & 7) ^ (fm & 7)) << 3;                       \
    _Pragma("unroll")                                                         \
    for (int i = 0; i < 8; i++)                                               \
        af[i] = *(const short8*)(As + (sl) * ASLOT + (wm + i * 16 + fm) * BK + sa); \
    _Pragma("unroll")                                                         \
    for (int j = 0; j < 4; j++)                                               \
        bf[j] = *(const short8*)(Bs + (sl) * BSLOT + (wn + j * 16 + fm) * BK + sa);

#define MFMA32()                                                              \
    __builtin_amdgcn_s_setprio(1);                                            \
    _Pragma("unroll")                                                         \
    for (int i = 0; i < 8; i++)                                               \
        _Pragma("unroll")                                                     \
        for (int j = 0; j < 4; j++)                                           \
            acc[i][j] = __builtin_amdgcn_mfma_f32_16x16x32_bf16(              \
                af[i], bf[j], acc[i][j], 0, 0, 0);                            \
    __builtin_amdgcn_s_setprio(0);

#define TILE_MAIN(vm, sl, k3)                                                 \
    {                                                                         \
        asm volatile("s_waitcnt vmcnt(" #vm ")" ::: "memory");                \
        __builtin_amdgcn_s_barrier();                                         \
        short8 af[8], bf[4];                                                  \
        LOADFRAG(sl);                                                         \
        asm volatile("s_waitcnt lgkmcnt(0)" ::: "memory");                    \
        __builtin_amdgcn_s_barrier();                                         \
        STAGE(k3, sl);                                                        \
        __builtin_amdgcn_sched_barrier(0);                                    \
        MFMA32();                                                             \
    }

#define TILE_TAIL(vm, sl)                                                     \
    {                                                                         \
        asm volatile("s_waitcnt vmcnt(" #vm ")" ::: "memory");                \
        __builtin_amdgcn_s_barrier();                                         \
        short8 af[8], bf[4];                                                  \
        LOADFRAG(sl);                                                         \
        MFMA32();                                                             \
    }

    // prologue: fill the 3-deep ring (18 loads/wave in flight)
    STAGE(0 * BK, 0);
    STAGE(1 * BK, 1);
    STAGE(2 * BK, 2);

    int st   = 0;
    int kpre = 3 * BK;
#pragma unroll 1
    for (int t = 0; t <= NT - 4; ++t) {        // t = 0..60, stages tiles 3..63
        TILE_MAIN(12, st, kpre);
        kpre += BK;
        st = (st == 2) ? 0 : st + 1;
    }
    // tail: tiles 61 (slot1), 62 (slot2), 63 (slot0); drain 12 -> 6 -> 0
    TILE_TAIL(12, 1);
    TILE_TAIL(6, 2);
    TILE_TAIL(0, 0);

#undef STAGE
#undef LOADFRAG
#undef MFMA32
#undef TILE_MAIN
#undef TILE_TAIL

    // K-split reduction: group1 parks partials in LDS, group0 sums + stores.
    __syncthreads();                       // all ring reads done before reuse
    floatx4* red = (floatx4*)lds;          // 128 KiB used of 144
    if (g == 1) {
#pragma unroll
        for (int i = 0; i < 8; i++)
#pragma unroll
            for (int j = 0; j < 4; j++)
                red[(size_t)(w2 * 32 + i * 4 + j) * 64 + lane] = acc[i][j];
    }
    __syncthreads();
    if (g == 0) {
        // epilogue: C/D layout col = lane&15, row = (lane>>4)*4 + reg  [m89]
        const int cn = lane & 15;
        const int cm = (lane >> 4) << 2;
        float bv[4];
#pragma unroll
        for (int j = 0; j < 4; j++)
            bv[j] = bias[bn * BN + wn + j * 16 + cn];
#pragma unroll
        for (int i = 0; i < 8; i++) {
#pragma unroll
            for (int j = 0; j < 4; j++) {
                floatx4 p = red[(size_t)(w2 * 32 + i * 4 + j) * 64 + lane];
#pragma unroll
                for (int r = 0; r < 4; r++) acc[i][j][r] += p[r];
            }
#pragma unroll
            for (int r = 0; r < 4; r++) {
                int m = bm * BM + wm + i * 16 + cm + r;
                float* crow = C + (size_t)m * OUT_F + bn * BN + wn + cn;
#pragma unroll
                for (int j = 0; j < 4; j++)
                    crow[j * 16] = acc[i][j][r] + bv[j];
            }
        }
    }
}

extern "C" void kernel_launch(void* const* d_in, const int* in_sizes, int n_in,
                              void* d_out, int out_size, void* d_ws, size_t ws_size,
                              hipStream_t stream) {
    const float* x    = (const float*)d_in[0];   // [2048, 4096]
    const float* seed = (const float*)d_in[1];   // [4096, 4096]
    const float* da   = (const float*)d_in[2];   // [20]
    const float* db   = (const float*)d_in[3];   // [20]
    const float* bias = (const float*)d_in[4];   // [4096]
    float* out        = (float*)d_out;           // [2048, 4096]

    ushort* w_bf = (ushort*)d_ws;                      // 32 MiB
    ushort* x_bf = w_bf + (size_t)OUT_F * IN_F;        // 16 MiB

    // allow 144 KiB dynamic LDS (one-time host-side attribute; not a stream op)
    static bool lds_attr_set = false;
    if (!lds_attr_set) {
        hipFuncSetAttribute(reinterpret_cast<const void*>(gemm_bt_kernel),
                            hipFuncAttributeMaxDynamicSharedMemorySize,
                            LDS_BYTES);
        lds_attr_set = true;
    }

    transcribe_fused_kernel<<<WBLOCKS + XBLOCKS, 256, 0, stream>>>(
        (const float4*)seed, (const float4*)x, da, db,
        (short8*)w_bf, (short8*)x_bf);

    gemm_bt_kernel<<<dim3(32 * 8), dim3(512), LDS_BYTES, stream>>>(
        x_bf, w_bf, bias, out);
}